// Round 14
// baseline (240.981 us; speedup 1.0000x reference)
//
#include <hip/hip_runtime.h>
#include <hip/hip_bf16.h>

typedef unsigned int uint;
typedef unsigned short ushort;

#define N_NODES 60000
#define N_EDGES 600000
#define NREL 7
#define D_IN 64
#define DHID 128
#define LEPS 1e-5f
#define EMB_BLKS 938            // (N_NODES+63)/64
#define ROW_BLKS 469            // (N_NODES+127)/128
#define SCAT_BLKS 512           // scatter blocks inside k_trans8 (512 thr each)

typedef __attribute__((ext_vector_type(8))) short bf16x8v;   // 8 bf16 = 4 VGPRs
typedef __attribute__((ext_vector_type(4))) float f32x4v;    // MFMA accumulator

#define AS1C(p) ((const __attribute__((address_space(1))) void*)(p))
#define AS3(p)  ((__attribute__((address_space(3))) void*)(p))

__device__ __forceinline__ float bf2f(uint u16) {
    return __uint_as_float(u16 << 16);
}
__device__ __forceinline__ uint f2bf(float f) {
    uint u = __float_as_uint(f);
    uint lsb = (u >> 16) & 1u;
    u += 0x7fffu + lsb;
    return u >> 16;
}
__device__ __forceinline__ uint pack2(float a, float b) {
    return f2bf(a) | (f2bf(b) << 16);
}

// ===== prep: blocks 0..63 W transposes, 64..65 emb_W transpose, 66+ deg8 ======
__global__ __launch_bounds__(256) void k_prep(const float* __restrict__ relW,
                                              const float* __restrict__ rootW,
                                              const float* __restrict__ embW,
                                              const int* __restrict__ dst,
                                              const int* __restrict__ et,
                                              ushort* __restrict__ Btr,   // [2][8][128j][128k]
                                              ushort* __restrict__ Bte,   // [128][64]
                                              int* __restrict__ deg8) {
    __shared__ float t[64][65];
    const int tid = threadIdx.x;
    if (blockIdx.x < 64) {
        const int l  = blockIdx.x >> 5;
        const int b5 = blockIdx.x & 31;
        const int r  = b5 >> 2;              // 0..7 (7 = root)
        const int kt = (b5 >> 1) & 1;
        const int jt = b5 & 1;
        #pragma unroll
        for (int i = 0; i < 4; ++i) {
            const int idx = i * 256 + tid;   // 0..1023
            const int kr = idx >> 4;         // 0..63
            const int j4 = idx & 15;
            const int kg = kt * 64 + kr;
            const float* src = (r < 7)
                ? (relW + (((size_t)l * 7 + r) * 128 + kg) * 128 + jt * 64 + j4 * 4)
                : (rootW + ((size_t)l * 128 + kg) * 128 + jt * 64 + j4 * 4);
            const float4 v = *(const float4*)src;
            t[kr][j4 * 4 + 0] = v.x; t[kr][j4 * 4 + 1] = v.y;
            t[kr][j4 * 4 + 2] = v.z; t[kr][j4 * 4 + 3] = v.w;
        }
        __syncthreads();
        uint* btd = (uint*)Btr;
        #pragma unroll
        for (int i = 0; i < 8; ++i) {
            const int idx = i * 256 + tid;   // 0..2047
            const int jr = idx >> 5;         // 0..63
            const int kd = idx & 31;         // k-dword within 64-k tile
            const uint w = pack2(t[kd * 2][jr], t[kd * 2 + 1][jr]);
            btd[((size_t)(l * 8 + r) * 128 + jt * 64 + jr) * 64 + kt * 32 + kd] = w;
        }
    } else if (blockIdx.x < 66) {
        const int jt = blockIdx.x - 64;      // 0..1
        #pragma unroll
        for (int i = 0; i < 4; ++i) {
            const int idx = i * 256 + tid;
            const int kr = idx >> 4;
            const int j4 = idx & 15;
            const float4 v = *(const float4*)(embW + (size_t)kr * 128 + jt * 64 + j4 * 4);
            t[kr][j4 * 4 + 0] = v.x; t[kr][j4 * 4 + 1] = v.y;
            t[kr][j4 * 4 + 2] = v.z; t[kr][j4 * 4 + 3] = v.w;
        }
        __syncthreads();
        uint* btd = (uint*)Bte;
        #pragma unroll
        for (int i = 0; i < 8; ++i) {
            const int idx = i * 256 + tid;
            const int jr = idx >> 5;
            const int kd = idx & 31;
            const uint w = pack2(t[kd * 2][jr], t[kd * 2 + 1][jr]);
            btd[(size_t)(jt * 64 + jr) * 32 + kd] = w;
        }
    } else {
        for (int e = (blockIdx.x - 66) * 256 + tid; e < N_EDGES; e += 1024 * 256)
            atomicAdd(&deg8[dst[e] * 8 + et[e]], 1);
    }
}

// ===== scan: node degree derived from deg8 row sums, exclusive scan ==========
__global__ void k_scan1n(const int* __restrict__ deg8, int* __restrict__ rp,
                         int* __restrict__ bsum, int n) {
    __shared__ int s[256];
    const int t = threadIdx.x;
    const int i = blockIdx.x * 256 + t;
    int v = 0;
    if (i < n) {
        const int4 x = *(const int4*)(deg8 + (size_t)i * 8);
        const int4 y = *(const int4*)(deg8 + (size_t)i * 8 + 4);
        v = x.x + x.y + x.z + x.w + y.x + y.y + y.z + y.w;
    }
    s[t] = v;
    __syncthreads();
    for (int o = 1; o < 256; o <<= 1) {
        int uu = (t >= o) ? s[t - o] : 0;
        __syncthreads();
        s[t] += uu;
        __syncthreads();
    }
    if (i < n) rp[i] = s[t] - v;
    if (t == 255) bsum[blockIdx.x] = s[255];
}
__global__ void k_scanmid(int* __restrict__ bs, int nb) {
    __shared__ int s[256];
    __shared__ int carrys;
    const int t = threadIdx.x;
    if (t == 0) carrys = 0;
    __syncthreads();
    const int nch = (nb + 255) / 256;
    for (int ch = 0; ch < nch; ++ch) {
        const int i = ch * 256 + t;
        const int v = (i < nb) ? bs[i] : 0;
        s[t] = v;
        __syncthreads();
        for (int o = 1; o < 256; o <<= 1) {
            int uu = (t >= o) ? s[t - o] : 0;
            __syncthreads();
            s[t] += uu;
            __syncthreads();
        }
        const int carry = carrys;
        if (i < nb) bs[i] = s[t] - v + carry;
        __syncthreads();
        if (t == 255) carrys = carry + s[255];
        __syncthreads();
    }
}
// final scan add; also pre-initializes fill = rp (scatter atomic returns position)
__global__ void k_scanadd(int* __restrict__ a, const int* __restrict__ bsums,
                          int* __restrict__ fill, int n) {
    const int i = blockIdx.x * 256 + threadIdx.x;
    if (i < n) {
        const int v = a[i] + bsums[blockIdx.x];
        a[i] = v;
        fill[i] = v;
    }
    if (blockIdx.x == 0 && threadIdx.x == 0) a[n] = N_EDGES;
}

// ===== emb: h0 = clip(x,-10,10)@emb_W + emb_b (bf16), MFMA =====================
__global__ __launch_bounds__(256) void k_emb(const float* __restrict__ x,
                                             const ushort* __restrict__ Bte,
                                             const float* __restrict__ ebias,
                                             ushort* __restrict__ h) {
    __shared__ alignas(16) ushort sa[64 * 64];    // 8 KB
    __shared__ alignas(16) ushort sb[128 * 64];   // 16 KB
    const int tid = threadIdx.x;
    const int lane = tid & 63;
    const int wid = tid >> 6;
    const int wrow = wid >> 1, wcol = wid & 1;
    const int l15 = lane & 15, lh = lane >> 4;
    const int row0 = blockIdx.x * 64;

    #pragma unroll
    for (int i = 0; i < 2; ++i) {
        const int p = i * 256 + tid;
        const int row = p >> 3, gq = p & 7;
        const int n = min(row0 + row, N_NODES - 1);
        const float4 xa = *(const float4*)(x + (size_t)n * 64 + gq * 8);
        const float4 xb = *(const float4*)(x + (size_t)n * 64 + gq * 8 + 4);
        uint w[4];
        w[0] = pack2(fminf(fmaxf(xa.x, -10.f), 10.f), fminf(fmaxf(xa.y, -10.f), 10.f));
        w[1] = pack2(fminf(fmaxf(xa.z, -10.f), 10.f), fminf(fmaxf(xa.w, -10.f), 10.f));
        w[2] = pack2(fminf(fmaxf(xb.x, -10.f), 10.f), fminf(fmaxf(xb.y, -10.f), 10.f));
        w[3] = pack2(fminf(fmaxf(xb.z, -10.f), 10.f), fminf(fmaxf(xb.w, -10.f), 10.f));
        *(uint4*)&sa[(row * 8 + (gq ^ (row & 7))) * 8] = make_uint4(w[0], w[1], w[2], w[3]);
    }
    #pragma unroll
    for (int i = 0; i < 4; ++i) {
        const int p = i * 256 + tid;
        const int row = p >> 3, gq = p & 7;
        const uint4 v = *(const uint4*)((const uint*)Bte + (size_t)row * 32 + gq * 4);
        *(uint4*)&sb[(row * 8 + (gq ^ (row & 7))) * 8] = v;
    }
    float bv[4];
    #pragma unroll
    for (int fn = 0; fn < 4; ++fn) bv[fn] = ebias[wcol * 64 + fn * 16 + l15];
    __syncthreads();

    f32x4v acc[2][4];
    #pragma unroll
    for (int fm = 0; fm < 2; ++fm)
        #pragma unroll
        for (int fn = 0; fn < 4; ++fn)
            acc[fm][fn] = (f32x4v){0.f, 0.f, 0.f, 0.f};
    #pragma unroll
    for (int kh = 0; kh < 2; ++kh) {
        bf16x8v af[2], bfr[4];
        #pragma unroll
        for (int fm = 0; fm < 2; ++fm) {
            const int rowa = wrow * 32 + fm * 16 + l15;
            const int slot = (kh * 4 + lh) ^ (rowa & 7);
            af[fm] = *(const bf16x8v*)&sa[rowa * 64 + slot * 8];
        }
        #pragma unroll
        for (int fn = 0; fn < 4; ++fn) {
            const int rowb = wcol * 64 + fn * 16 + l15;
            const int slot = (kh * 4 + lh) ^ (rowb & 7);
            bfr[fn] = *(const bf16x8v*)&sb[rowb * 64 + slot * 8];
        }
        #pragma unroll
        for (int fm = 0; fm < 2; ++fm)
            #pragma unroll
            for (int fn = 0; fn < 4; ++fn)
                acc[fm][fn] = __builtin_amdgcn_mfma_f32_16x16x32_bf16(
                    af[fm], bfr[fn], acc[fm][fn], 0, 0, 0);
    }
    #pragma unroll
    for (int fm = 0; fm < 2; ++fm)
        #pragma unroll
        for (int r = 0; r < 4; ++r) {
            const int row = row0 + wrow * 32 + fm * 16 + lh * 4 + r;
            if (row < N_NODES) {
                #pragma unroll
                for (int fn = 0; fn < 4; ++fn) {
                    const int col = wcol * 64 + fn * 16 + l15;
                    h[(size_t)row * 128 + col] = (ushort)f2bf(acc[fm][fn][r] + bv[fn]);
                }
            }
        }
}

// ===== trans8: blocks < nscat do CSR scatter; rest: ONE block = 128 h-rows,
// loops ALL 8 bj from the same LDS A-tile (h fetched once). SWAPPED MFMA
// operands (A=W rows j, B=h rows n) so C/D reg quad = 4 consecutive j ->
// uint2 (8B) T stores. Pipeline: stageB(next) -> MFMA -> stores ->
// vmcnt(8)+barrier (drains only the 4 B-loads; stores retire in shadow). ====
// entry = (rel<<20) | (rel*N_NODES + src)
__global__ __launch_bounds__(512) void k_trans8(const ushort* __restrict__ h16,
                                                const ushort* __restrict__ Btr,  // [8][128j][128k]
                                                ushort* __restrict__ T16,        // [8][N][128]
                                                const int* __restrict__ src,
                                                const int* __restrict__ dst,
                                                const int* __restrict__ et,
                                                int* __restrict__ fill,
                                                uint* __restrict__ csr32,
                                                int nscat) {
    __shared__ alignas(16) ushort sa[2][8192];      // 32 KB: h-tile [kt][...]
    __shared__ alignas(16) ushort sb[2][2][8192];   // 64 KB: W [buf][kt][...]
    const int tid = threadIdx.x;
    if (blockIdx.x < nscat) {
        for (int e = blockIdx.x * 512 + tid; e < N_EDGES; e += SCAT_BLKS * 512) {
            const int d = dst[e];
            const int r = et[e];
            const int p = atomicAdd(&fill[d], 1);
            csr32[p] = ((uint)r << 20) | (uint)(r * N_NODES + src[e]);
        }
        return;
    }
    const int row0 = (blockIdx.x - nscat) * 128;
    const int lane = tid & 63;
    const int wid = tid >> 6;
    const int wrow = wid >> 1;        // 0..3: 32-j band
    const int wcol = wid & 1;         // 0..1: 64-node band
    const int l15 = lane & 15, lh = lane >> 4;

    // staging: thread covers granules {tid, tid+512} of each 1024-granule tile
    int rA[2], gA[2], aw[2];
    #pragma unroll
    for (int hf = 0; hf < 2; ++hf) {
        const int p = hf * 512 + tid;
        const int r = p >> 3;
        rA[hf] = r;
        gA[hf] = (p & 7) ^ (r & 7);
        aw[hf] = min(row0 + r, N_NODES - 1);
    }
    auto stageA = [&]() {
        #pragma unroll
        for (int kt = 0; kt < 2; ++kt)
            #pragma unroll
            for (int hf = 0; hf < 2; ++hf) {
                const ushort* ga = h16 + (size_t)aw[hf] * 128 + kt * 64 + gA[hf] * 8;
                __builtin_amdgcn_global_load_lds(AS1C(ga),
                    AS3(&sa[kt][(hf * 512 + tid) * 8]), 16, 0, 0);
            }
    };
    auto stageB = [&](int buf, int bj) {
        #pragma unroll
        for (int kt = 0; kt < 2; ++kt)
            #pragma unroll
            for (int hf = 0; hf < 2; ++hf) {
                const ushort* gb = Btr + ((size_t)bj * 128 + rA[hf]) * 128 + kt * 64 + gA[hf] * 8;
                __builtin_amdgcn_global_load_lds(AS1C(gb),
                    AS3(&sb[buf][kt][(hf * 512 + tid) * 8]), 16, 0, 0);
            }
    };

    stageA();          // 4 outstanding
    stageB(0, 0);      // 8 outstanding
    asm volatile("s_waitcnt vmcnt(0)\n\ts_barrier" ::: "memory");

    #pragma unroll 1
    for (int bj = 0; bj < 8; ++bj) {
        const int cur = bj & 1;
        if (bj < 7) stageB(cur ^ 1, bj + 1);   // 4 loads, drained at loop tail
        f32x4v acc[2][4];
        #pragma unroll
        for (int fm = 0; fm < 2; ++fm)
            #pragma unroll
            for (int fn = 0; fn < 4; ++fn)
                acc[fm][fn] = (f32x4v){0.f, 0.f, 0.f, 0.f};
        #pragma unroll
        for (int kt = 0; kt < 2; ++kt)
            #pragma unroll
            for (int kh = 0; kh < 2; ++kh) {
                bf16x8v af[2], bfr[4];
                #pragma unroll
                for (int fm = 0; fm < 2; ++fm) {        // A = W rows (j)
                    const int rowj = wrow * 32 + fm * 16 + l15;
                    const int slot = (kh * 4 + lh) ^ (rowj & 7);
                    af[fm] = *(const bf16x8v*)&sb[cur][kt][rowj * 64 + slot * 8];
                }
                #pragma unroll
                for (int fn = 0; fn < 4; ++fn) {        // B = h rows (n)
                    const int rown = wcol * 64 + fn * 16 + l15;
                    const int slot = (kh * 4 + lh) ^ (rown & 7);
                    bfr[fn] = *(const bf16x8v*)&sa[kt][rown * 64 + slot * 8];
                }
                #pragma unroll
                for (int fm = 0; fm < 2; ++fm)
                    #pragma unroll
                    for (int fn = 0; fn < 4; ++fn)
                        acc[fm][fn] = __builtin_amdgcn_mfma_f32_16x16x32_bf16(
                            af[fm], bfr[fn], acc[fm][fn], 0, 0, 0);
            }
        // store: lane owns node n = wcol*64+fn*16+l15, reg quad = 4 consec j
        #pragma unroll
        for (int fn = 0; fn < 4; ++fn) {
            const int n = row0 + wcol * 64 + fn * 16 + l15;
            if (n < N_NODES) {
                ushort* tp = T16 + ((size_t)bj * N_NODES + n) * 128 + wrow * 32 + lh * 4;
                #pragma unroll
                for (int fm = 0; fm < 2; ++fm) {
                    uint2 o;
                    o.x = pack2(acc[fm][fn][0], acc[fm][fn][1]);
                    o.y = pack2(acc[fm][fn][2], acc[fm][fn][3]);
                    *(uint2*)(tp + fm * 16) = o;
                }
            }
        }
        if (bj < 7)
            asm volatile("s_waitcnt vmcnt(8)\n\ts_barrier" ::: "memory");
    }
}

// ===== gather: out[n] = LNReLU( sum_e w*T[idx_e] + T[root][n] + bias ) ========
__global__ __launch_bounds__(256) void k_gather(const uint* __restrict__ T32,  // [8][N][64] dw
                                                const int* __restrict__ rp,
                                                const int* __restrict__ deg8,
                                                const uint* __restrict__ csr32,
                                                const float* __restrict__ bias,
                                                const float* __restrict__ g,
                                                const float* __restrict__ bb,
                                                uint* __restrict__ hout) {
    __shared__ float sinv[4][8];
    const int wave = (blockIdx.x * 256 + threadIdx.x) >> 6;
    const int lane = threadIdx.x & 63;
    const int wid = (threadIdx.x >> 6) & 3;
    const int nwaves = gridDim.x * 4;
    const float2 bias2 = *(const float2*)(bias + 2 * lane);
    const float2 g2 = *(const float2*)(g + 2 * lane);
    const float2 b2 = *(const float2*)(bb + 2 * lane);
    #pragma unroll 1
    for (int n0 = wave; n0 < N_NODES; n0 += nwaves) {
        const int n = __builtin_amdgcn_readfirstlane(n0);
        const int beg = __builtin_amdgcn_readfirstlane(rp[n]);
        const int end = __builtin_amdgcn_readfirstlane(rp[n + 1]);
        if (lane < 8) {
            const int c = deg8[(size_t)n * 8 + lane];
            sinv[wid][lane] = 1.0f / (float)max(c, 1);
        }
        float ax = 0.f, ay = 0.f;
        #pragma unroll 1
        for (int e = beg; e < end; e += 8) {            // masked 8-deep batch
            const int4 c0 = *(const int4*)(csr32 + e);
            const int4 c1 = *(const int4*)(csr32 + e + 4);
            int t[8] = {c0.x, c0.y, c0.z, c0.w, c1.x, c1.y, c1.z, c1.w};
            #pragma unroll
            for (int q = 0; q < 8; ++q) t[q] = __builtin_amdgcn_readfirstlane(t[q]);
            uint v[8];
            #pragma unroll
            for (int q = 0; q < 8; ++q)
                if (e + q < end) v[q] = T32[(size_t)(t[q] & 0xFFFFF) * 64 + lane];
            #pragma unroll
            for (int q = 0; q < 8; ++q)
                if (e + q < end) {
                    const float w = sinv[wid][(t[q] >> 20) & 7];
                    ax += w * __uint_as_float(v[q] << 16);
                    ay += w * __uint_as_float(v[q] & 0xFFFF0000u);
                }
        }
        const uint vr = T32[((size_t)7 * N_NODES + n) * 64 + lane];   // root term
        const float c0f = ax + bf2f(vr & 0xFFFFu) + bias2.x;
        const float c1f = ay + bf2f(vr >> 16) + bias2.y;
        float s = c0f + c1f, sq = c0f * c0f + c1f * c1f;
        #pragma unroll
        for (int o = 1; o < 64; o <<= 1) {
            s += __shfl_xor(s, o, 64);
            sq += __shfl_xor(sq, o, 64);
        }
        const float mean = s * (1.f / 128.f);
        const float var = sq * (1.f / 128.f) - mean * mean;
        const float rs = rsqrtf(var + LEPS);
        const float y0 = fmaxf((c0f - mean) * rs * g2.x + b2.x, 0.f);
        const float y1 = fmaxf((c1f - mean) * rs * g2.y + b2.y, 0.f);
        hout[(size_t)n * 64 + lane] = pack2(y0, y1);
    }
}

// ===== classifier: MFMA h@W1 + in-register LN/ReLU/W2-dot =====================
__global__ __launch_bounds__(256) void k_cls(const ushort* __restrict__ h16,
                                             const float* __restrict__ W1,
                                             const float* __restrict__ b1,
                                             const float* __restrict__ lg,
                                             const float* __restrict__ lb,
                                             const float* __restrict__ W2,
                                             const float* __restrict__ b2,
                                             float* __restrict__ outp, int nrows) {
    __shared__ ushort Bs[16 * 64 * 8];   // 16 KB
    const int tid = threadIdx.x;
    #pragma unroll
    for (int i = 0; i < 8; ++i) {
        const int q = i * 256 + tid;
        const int k = q >> 4;
        const int j0 = (q & 15) * 4;
        const float4 w = *(const float4*)(W1 + (size_t)k * 64 + j0);
        const int gg = k >> 3, kp = k & 7;
        const int jx = (gg & 3) << 4;
        Bs[(gg * 64 + ((j0 + 0) ^ jx)) * 8 + kp] = (ushort)f2bf(w.x);
        Bs[(gg * 64 + ((j0 + 1) ^ jx)) * 8 + kp] = (ushort)f2bf(w.y);
        Bs[(gg * 64 + ((j0 + 2) ^ jx)) * 8 + kp] = (ushort)f2bf(w.z);
        Bs[(gg * 64 + ((j0 + 3) ^ jx)) * 8 + kp] = (ushort)f2bf(w.w);
    }
    const int lane = tid & 63, wid = tid >> 6;
    const int l15 = lane & 15, lh = lane >> 4;
    float lgv[4], lbv[4], w2v[4], b1v[4];
    #pragma unroll
    for (int fn = 0; fn < 4; ++fn) {
        const int col = fn * 16 + l15;
        lgv[fn] = lg[col]; lbv[fn] = lb[col]; w2v[fn] = W2[col]; b1v[fn] = b1[col];
    }
    const float b2v = b2[0];
    __syncthreads();

    const int row0 = blockIdx.x * 128;
    f32x4v acc[2][4];
    #pragma unroll
    for (int fm = 0; fm < 2; ++fm)
        #pragma unroll
        for (int fn = 0; fn < 4; ++fn)
            acc[fm][fn] = (f32x4v){0.f, 0.f, 0.f, 0.f};

    #pragma unroll
    for (int kk = 0; kk < 4; ++kk) {
        bf16x8v af[2], bfr[4];
        #pragma unroll
        for (int fm = 0; fm < 2; ++fm) {
            const int row = min(row0 + wid * 32 + fm * 16 + l15, nrows - 1);
            af[fm] = *(const bf16x8v*)(h16 + (size_t)row * 128 + kk * 32 + lh * 8);
        }
        #pragma unroll
        for (int fn = 0; fn < 4; ++fn) {
            const int gg = kk * 4 + lh;
            const int jc = fn * 16 + l15;
            bfr[fn] = *(const bf16x8v*)&Bs[(gg * 64 + (jc ^ ((gg & 3) << 4))) * 8];
        }
        #pragma unroll
        for (int fm = 0; fm < 2; ++fm)
            #pragma unroll
            for (int fn = 0; fn < 4; ++fn)
                acc[fm][fn] = __builtin_amdgcn_mfma_f32_16x16x32_bf16(
                    af[fm], bfr[fn], acc[fm][fn], 0, 0, 0);
    }

    #pragma unroll
    for (int fm = 0; fm < 2; ++fm)
        #pragma unroll
        for (int r = 0; r < 4; ++r) {
            float cv[4];
            float s = 0.f, sq = 0.f;
            #pragma unroll
            for (int fn = 0; fn < 4; ++fn) {
                cv[fn] = acc[fm][fn][r] + b1v[fn];
                s += cv[fn]; sq += cv[fn] * cv[fn];
            }
            s += __shfl_xor(s, 1, 64); sq += __shfl_xor(sq, 1, 64);
            s += __shfl_xor(s, 2, 64); sq += __shfl_xor(sq, 2, 64);
            s += __shfl_xor(s, 4, 64); sq += __shfl_xor(sq, 4, 64);
            s += __shfl_xor(s, 8, 64); sq += __shfl_xor(sq, 8, 64);
            const float mean = s * (1.f / 64.f);
            const float var = sq * (1.f / 64.f) - mean * mean;
            const float rs = rsqrtf(var + LEPS);
            float dot = 0.f;
            #pragma unroll
            for (int fn = 0; fn < 4; ++fn)
                dot += fmaxf((cv[fn] - mean) * rs * lgv[fn] + lbv[fn], 0.f) * w2v[fn];
            dot += __shfl_xor(dot, 1, 64);
            dot += __shfl_xor(dot, 2, 64);
            dot += __shfl_xor(dot, 4, 64);
            dot += __shfl_xor(dot, 8, 64);
            const int row = row0 + wid * 32 + fm * 16 + lh * 4 + r;
            if (l15 == 0 && row < nrows) outp[row] = dot + b2v;
        }
}

extern "C" void kernel_launch(void* const* d_in, const int* in_sizes, int n_in,
                              void* d_out, int out_size, void* d_ws, size_t ws_size,
                              hipStream_t stream) {
    const float* x      = (const float*)d_in[0];
    const int*   eidx   = (const int*)d_in[1];
    const int*   etype  = (const int*)d_in[2];
    const float* emb_W  = (const float*)d_in[3];
    const float* emb_b  = (const float*)d_in[4];
    const float* rel_W  = (const float*)d_in[5];
    const float* root_W = (const float*)d_in[6];
    const float* conv_b = (const float*)d_in[7];
    const float* ln_g   = (const float*)d_in[8];
    const float* ln_b   = (const float*)d_in[9];
    const float* cls_W1 = (const float*)d_in[10];
    const float* cls_b1 = (const float*)d_in[11];
    const float* cls_lg = (const float*)d_in[12];
    const float* cls_lb = (const float*)d_in[13];
    const float* cls_W2 = (const float*)d_in[14];
    const float* cls_b2 = (const float*)d_in[15];

    const int* srcv = eidx;
    const int* dstv = eidx + N_EDGES;

    // workspace layout (~144 MB)
    char* ws = (char*)d_ws;
    size_t off = 0;
    auto alloc = [&](size_t bytes) { void* p = ws + off; off += (bytes + 255) & ~(size_t)255; return p; };
    ushort* h     = (ushort*)alloc((size_t)N_NODES * 128 * 2);          // bf16 h
    ushort* T     = (ushort*)alloc((size_t)8 * N_NODES * 128 * 2);      // bf16 T [8][N][128]
    int*    rp    = (int*)alloc((size_t)(N_NODES + 1) * 4);
    int*    cnts  = (int*)alloc((size_t)(N_NODES * 9) * 4);             // deg8 | fill
    uint*   csr32 = (uint*)alloc((size_t)(N_EDGES + 8) * 4);
    ushort* Btr   = (ushort*)alloc((size_t)2 * 8 * 128 * 128 * 2);      // bf16 W^T
    ushort* Bte   = (ushort*)alloc((size_t)128 * 64 * 2);               // bf16 emb_W^T
    int*    bs    = (int*)alloc(4096);
    int*    deg8  = cnts;
    int*    fill  = cnts + N_NODES * 8;
    (void)ws_size; (void)n_in; (void)in_sizes; (void)out_size;

    const int SB = (N_NODES + 255) / 256;         // 235

    hipMemsetAsync(deg8, 0, (size_t)(N_NODES * 8) * 4, stream);
    k_prep<<<66 + 1024, 256, 0, stream>>>(rel_W, root_W, emb_W, dstv, etype,
                                          Btr, Bte, deg8);
    k_scan1n<<<SB, 256, 0, stream>>>(deg8, rp, bs, N_NODES);
    k_scanmid<<<1, 256, 0, stream>>>(bs, SB);
    k_scanadd<<<SB, 256, 0, stream>>>(rp, bs, fill, N_NODES);
    k_emb<<<EMB_BLKS, 256, 0, stream>>>(x, Bte, emb_b, h);

    // layer 0: scatter co-scheduled with transform (independent work)
    k_trans8<<<SCAT_BLKS + ROW_BLKS, 512, 0, stream>>>(
        h, Btr, T, srcv, dstv, etype, fill, csr32, SCAT_BLKS);
    k_gather<<<2048, 256, 0, stream>>>(
        (const uint*)T, rp, deg8, csr32,
        conv_b, ln_g, ln_b, (uint*)h);

    // layer 1: transform only
    k_trans8<<<ROW_BLKS, 512, 0, stream>>>(
        h, Btr + (size_t)131072, T, srcv, dstv, etype, fill, csr32, 0);
    k_gather<<<2048, 256, 0, stream>>>(
        (const uint*)T, rp, deg8, csr32,
        conv_b + 128, ln_g + 128, ln_b + 128, (uint*)h);

    k_cls<<<469, 256, 0, stream>>>(h, cls_W1, cls_b1, cls_lg, cls_lb,
                                   cls_W2, cls_b2, (float*)d_out, N_NODES);
}

// Round 15
// 217.666 us; speedup vs baseline: 1.1071x; 1.1071x over previous
//
#include <hip/hip_runtime.h>
#include <hip/hip_bf16.h>

typedef unsigned int uint;
typedef unsigned short ushort;

#define N_NODES 60000
#define N_EDGES 600000
#define NREL 7
#define D_IN 64
#define DHID 128
#define LEPS 1e-5f
#define EMB_BLKS 938            // (N_NODES+63)/64
#define ROW_BLKS 469            // (N_NODES+127)/128
#define SCAT_BLKS 512           // scatter blocks inside k_trans8 (512 thr each)

typedef __attribute__((ext_vector_type(8))) short bf16x8v;   // 8 bf16 = 4 VGPRs
typedef __attribute__((ext_vector_type(4))) float f32x4v;    // MFMA accumulator

#define AS1C(p) ((const __attribute__((address_space(1))) void*)(p))
#define AS3(p)  ((__attribute__((address_space(3))) void*)(p))

__device__ __forceinline__ float bf2f(uint u16) {
    return __uint_as_float(u16 << 16);
}
__device__ __forceinline__ uint f2bf(float f) {
    uint u = __float_as_uint(f);
    uint lsb = (u >> 16) & 1u;
    u += 0x7fffu + lsb;
    return u >> 16;
}
__device__ __forceinline__ uint pack2(float a, float b) {
    return f2bf(a) | (f2bf(b) << 16);
}

// ===== prep: blocks 0..63 W transposes, 64..65 emb_W transpose, 66+ deg8 ======
__global__ __launch_bounds__(256) void k_prep(const float* __restrict__ relW,
                                              const float* __restrict__ rootW,
                                              const float* __restrict__ embW,
                                              const int* __restrict__ dst,
                                              const int* __restrict__ et,
                                              ushort* __restrict__ Btr,   // [2][8][128j][128k]
                                              ushort* __restrict__ Bte,   // [128][64]
                                              int* __restrict__ deg8) {
    __shared__ float t[64][65];
    const int tid = threadIdx.x;
    if (blockIdx.x < 64) {
        const int l  = blockIdx.x >> 5;
        const int b5 = blockIdx.x & 31;
        const int r  = b5 >> 2;              // 0..7 (7 = root)
        const int kt = (b5 >> 1) & 1;
        const int jt = b5 & 1;
        #pragma unroll
        for (int i = 0; i < 4; ++i) {
            const int idx = i * 256 + tid;   // 0..1023
            const int kr = idx >> 4;         // 0..63
            const int j4 = idx & 15;
            const int kg = kt * 64 + kr;
            const float* src = (r < 7)
                ? (relW + (((size_t)l * 7 + r) * 128 + kg) * 128 + jt * 64 + j4 * 4)
                : (rootW + ((size_t)l * 128 + kg) * 128 + jt * 64 + j4 * 4);
            const float4 v = *(const float4*)src;
            t[kr][j4 * 4 + 0] = v.x; t[kr][j4 * 4 + 1] = v.y;
            t[kr][j4 * 4 + 2] = v.z; t[kr][j4 * 4 + 3] = v.w;
        }
        __syncthreads();
        uint* btd = (uint*)Btr;
        #pragma unroll
        for (int i = 0; i < 8; ++i) {
            const int idx = i * 256 + tid;   // 0..2047
            const int jr = idx >> 5;         // 0..63
            const int kd = idx & 31;         // k-dword within 64-k tile
            const uint w = pack2(t[kd * 2][jr], t[kd * 2 + 1][jr]);
            btd[((size_t)(l * 8 + r) * 128 + jt * 64 + jr) * 64 + kt * 32 + kd] = w;
        }
    } else if (blockIdx.x < 66) {
        const int jt = blockIdx.x - 64;      // 0..1
        #pragma unroll
        for (int i = 0; i < 4; ++i) {
            const int idx = i * 256 + tid;
            const int kr = idx >> 4;
            const int j4 = idx & 15;
            const float4 v = *(const float4*)(embW + (size_t)kr * 128 + jt * 64 + j4 * 4);
            t[kr][j4 * 4 + 0] = v.x; t[kr][j4 * 4 + 1] = v.y;
            t[kr][j4 * 4 + 2] = v.z; t[kr][j4 * 4 + 3] = v.w;
        }
        __syncthreads();
        uint* btd = (uint*)Bte;
        #pragma unroll
        for (int i = 0; i < 8; ++i) {
            const int idx = i * 256 + tid;
            const int jr = idx >> 5;
            const int kd = idx & 31;
            const uint w = pack2(t[kd * 2][jr], t[kd * 2 + 1][jr]);
            btd[(size_t)(jt * 64 + jr) * 32 + kd] = w;
        }
    } else {
        for (int e = (blockIdx.x - 66) * 256 + tid; e < N_EDGES; e += 1024 * 256)
            atomicAdd(&deg8[dst[e] * 8 + et[e]], 1);
    }
}

// ===== scan: node degree derived from deg8 row sums, exclusive scan ==========
__global__ void k_scan1n(const int* __restrict__ deg8, int* __restrict__ rp,
                         int* __restrict__ bsum, int n) {
    __shared__ int s[256];
    const int t = threadIdx.x;
    const int i = blockIdx.x * 256 + t;
    int v = 0;
    if (i < n) {
        const int4 x = *(const int4*)(deg8 + (size_t)i * 8);
        const int4 y = *(const int4*)(deg8 + (size_t)i * 8 + 4);
        v = x.x + x.y + x.z + x.w + y.x + y.y + y.z + y.w;
    }
    s[t] = v;
    __syncthreads();
    for (int o = 1; o < 256; o <<= 1) {
        int uu = (t >= o) ? s[t - o] : 0;
        __syncthreads();
        s[t] += uu;
        __syncthreads();
    }
    if (i < n) rp[i] = s[t] - v;
    if (t == 255) bsum[blockIdx.x] = s[255];
}
__global__ void k_scanmid(int* __restrict__ bs, int nb) {
    __shared__ int s[256];
    __shared__ int carrys;
    const int t = threadIdx.x;
    if (t == 0) carrys = 0;
    __syncthreads();
    const int nch = (nb + 255) / 256;
    for (int ch = 0; ch < nch; ++ch) {
        const int i = ch * 256 + t;
        const int v = (i < nb) ? bs[i] : 0;
        s[t] = v;
        __syncthreads();
        for (int o = 1; o < 256; o <<= 1) {
            int uu = (t >= o) ? s[t - o] : 0;
            __syncthreads();
            s[t] += uu;
            __syncthreads();
        }
        const int carry = carrys;
        if (i < nb) bs[i] = s[t] - v + carry;
        __syncthreads();
        if (t == 255) carrys = carry + s[255];
        __syncthreads();
    }
}
// final scan add; also pre-initializes fill = rp (scatter atomic returns position)
__global__ void k_scanadd(int* __restrict__ a, const int* __restrict__ bsums,
                          int* __restrict__ fill, int n) {
    const int i = blockIdx.x * 256 + threadIdx.x;
    if (i < n) {
        const int v = a[i] + bsums[blockIdx.x];
        a[i] = v;
        fill[i] = v;
    }
    if (blockIdx.x == 0 && threadIdx.x == 0) a[n] = N_EDGES;
}

// ===== emb: h0 = clip(x,-10,10)@emb_W + emb_b (bf16), MFMA =====================
__global__ __launch_bounds__(256) void k_emb(const float* __restrict__ x,
                                             const ushort* __restrict__ Bte,
                                             const float* __restrict__ ebias,
                                             ushort* __restrict__ h) {
    __shared__ alignas(16) ushort sa[64 * 64];    // 8 KB
    __shared__ alignas(16) ushort sb[128 * 64];   // 16 KB
    const int tid = threadIdx.x;
    const int lane = tid & 63;
    const int wid = tid >> 6;
    const int wrow = wid >> 1, wcol = wid & 1;
    const int l15 = lane & 15, lh = lane >> 4;
    const int row0 = blockIdx.x * 64;

    #pragma unroll
    for (int i = 0; i < 2; ++i) {
        const int p = i * 256 + tid;
        const int row = p >> 3, gq = p & 7;
        const int n = min(row0 + row, N_NODES - 1);
        const float4 xa = *(const float4*)(x + (size_t)n * 64 + gq * 8);
        const float4 xb = *(const float4*)(x + (size_t)n * 64 + gq * 8 + 4);
        uint w[4];
        w[0] = pack2(fminf(fmaxf(xa.x, -10.f), 10.f), fminf(fmaxf(xa.y, -10.f), 10.f));
        w[1] = pack2(fminf(fmaxf(xa.z, -10.f), 10.f), fminf(fmaxf(xa.w, -10.f), 10.f));
        w[2] = pack2(fminf(fmaxf(xb.x, -10.f), 10.f), fminf(fmaxf(xb.y, -10.f), 10.f));
        w[3] = pack2(fminf(fmaxf(xb.z, -10.f), 10.f), fminf(fmaxf(xb.w, -10.f), 10.f));
        *(uint4*)&sa[(row * 8 + (gq ^ (row & 7))) * 8] = make_uint4(w[0], w[1], w[2], w[3]);
    }
    #pragma unroll
    for (int i = 0; i < 4; ++i) {
        const int p = i * 256 + tid;
        const int row = p >> 3, gq = p & 7;
        const uint4 v = *(const uint4*)((const uint*)Bte + (size_t)row * 32 + gq * 4);
        *(uint4*)&sb[(row * 8 + (gq ^ (row & 7))) * 8] = v;
    }
    float bv[4];
    #pragma unroll
    for (int fn = 0; fn < 4; ++fn) bv[fn] = ebias[wcol * 64 + fn * 16 + l15];
    __syncthreads();

    f32x4v acc[2][4];
    #pragma unroll
    for (int fm = 0; fm < 2; ++fm)
        #pragma unroll
        for (int fn = 0; fn < 4; ++fn)
            acc[fm][fn] = (f32x4v){0.f, 0.f, 0.f, 0.f};
    #pragma unroll
    for (int kh = 0; kh < 2; ++kh) {
        bf16x8v af[2], bfr[4];
        #pragma unroll
        for (int fm = 0; fm < 2; ++fm) {
            const int rowa = wrow * 32 + fm * 16 + l15;
            const int slot = (kh * 4 + lh) ^ (rowa & 7);
            af[fm] = *(const bf16x8v*)&sa[rowa * 64 + slot * 8];
        }
        #pragma unroll
        for (int fn = 0; fn < 4; ++fn) {
            const int rowb = wcol * 64 + fn * 16 + l15;
            const int slot = (kh * 4 + lh) ^ (rowb & 7);
            bfr[fn] = *(const bf16x8v*)&sb[rowb * 64 + slot * 8];
        }
        #pragma unroll
        for (int fm = 0; fm < 2; ++fm)
            #pragma unroll
            for (int fn = 0; fn < 4; ++fn)
                acc[fm][fn] = __builtin_amdgcn_mfma_f32_16x16x32_bf16(
                    af[fm], bfr[fn], acc[fm][fn], 0, 0, 0);
    }
    #pragma unroll
    for (int fm = 0; fm < 2; ++fm)
        #pragma unroll
        for (int r = 0; r < 4; ++r) {
            const int row = row0 + wrow * 32 + fm * 16 + lh * 4 + r;
            if (row < N_NODES) {
                #pragma unroll
                for (int fn = 0; fn < 4; ++fn) {
                    const int col = wcol * 64 + fn * 16 + l15;
                    h[(size_t)row * 128 + col] = (ushort)f2bf(acc[fm][fn][r] + bv[fn]);
                }
            }
        }
}

// ===== trans8: blocks < nscat do CSR scatter; rest: ONE block = 128 h-rows,
// loops ALL 8 bj from the same LDS A-tile (h fetched once per layer).
// Round-13 operand order (A=h rows n, B=W rows j -> lane-contiguous 32B store
// segments) + round-14 pipeline: stageB(next) -> MFMA -> stores ->
// vmcnt(32)+barrier (retires the 4 loads; the 32 newest stores drain in the
// shadow of the next bj's MFMA). =============================================
// entry = (rel<<20) | (rel*N_NODES + src)
__global__ __launch_bounds__(512) void k_trans8(const ushort* __restrict__ h16,
                                                const ushort* __restrict__ Btr,  // [8][128j][128k]
                                                ushort* __restrict__ T16,        // [8][N][128]
                                                const int* __restrict__ src,
                                                const int* __restrict__ dst,
                                                const int* __restrict__ et,
                                                int* __restrict__ fill,
                                                uint* __restrict__ csr32,
                                                int nscat) {
    __shared__ alignas(16) ushort sa[2][8192];      // 32 KB: h-tile [kt][...]
    __shared__ alignas(16) ushort sb[2][2][8192];   // 64 KB: W [buf][kt][...]
    const int tid = threadIdx.x;
    if (blockIdx.x < nscat) {
        for (int e = blockIdx.x * 512 + tid; e < N_EDGES; e += SCAT_BLKS * 512) {
            const int d = dst[e];
            const int r = et[e];
            const int p = atomicAdd(&fill[d], 1);
            csr32[p] = ((uint)r << 20) | (uint)(r * N_NODES + src[e]);
        }
        return;
    }
    const int row0 = (blockIdx.x - nscat) * 128;
    const int lane = tid & 63;
    const int wid = tid >> 6;
    const int wrow = wid >> 1;        // 0..3: 32-node band
    const int wcol = wid & 1;         // 0..1: 64-j band
    const int l15 = lane & 15, lh = lane >> 4;

    // staging: thread covers granules {tid, tid+512} of each 1024-granule tile
    int rA[2], gA[2], aw[2];
    #pragma unroll
    for (int hf = 0; hf < 2; ++hf) {
        const int p = hf * 512 + tid;
        const int r = p >> 3;
        rA[hf] = r;
        gA[hf] = (p & 7) ^ (r & 7);
        aw[hf] = min(row0 + r, N_NODES - 1);
    }
    auto stageA = [&]() {
        #pragma unroll
        for (int kt = 0; kt < 2; ++kt)
            #pragma unroll
            for (int hf = 0; hf < 2; ++hf) {
                const ushort* ga = h16 + (size_t)aw[hf] * 128 + kt * 64 + gA[hf] * 8;
                __builtin_amdgcn_global_load_lds(AS1C(ga),
                    AS3(&sa[kt][(hf * 512 + tid) * 8]), 16, 0, 0);
            }
    };
    auto stageB = [&](int buf, int bj) {
        #pragma unroll
        for (int kt = 0; kt < 2; ++kt)
            #pragma unroll
            for (int hf = 0; hf < 2; ++hf) {
                const ushort* gb = Btr + ((size_t)bj * 128 + rA[hf]) * 128 + kt * 64 + gA[hf] * 8;
                __builtin_amdgcn_global_load_lds(AS1C(gb),
                    AS3(&sb[buf][kt][(hf * 512 + tid) * 8]), 16, 0, 0);
            }
    };

    stageA();          // 4 outstanding
    stageB(0, 0);      // 8 outstanding
    asm volatile("s_waitcnt vmcnt(0)\n\ts_barrier" ::: "memory");

    #pragma unroll 1
    for (int bj = 0; bj < 8; ++bj) {
        const int cur = bj & 1;
        if (bj < 7) stageB(cur ^ 1, bj + 1);   // 4 loads into sb[cur^1]
        f32x4v acc[2][4];
        #pragma unroll
        for (int fm = 0; fm < 2; ++fm)
            #pragma unroll
            for (int fn = 0; fn < 4; ++fn)
                acc[fm][fn] = (f32x4v){0.f, 0.f, 0.f, 0.f};
        #pragma unroll
        for (int kt = 0; kt < 2; ++kt)
            #pragma unroll
            for (int kh = 0; kh < 2; ++kh) {
                bf16x8v af[2], bfr[4];
                #pragma unroll
                for (int fm = 0; fm < 2; ++fm) {        // A = h rows (n)
                    const int rowa = wrow * 32 + fm * 16 + l15;
                    const int slot = (kh * 4 + lh) ^ (rowa & 7);
                    af[fm] = *(const bf16x8v*)&sa[kt][rowa * 64 + slot * 8];
                }
                #pragma unroll
                for (int fn = 0; fn < 4; ++fn) {        // B = W rows (j)
                    const int rowb = wcol * 64 + fn * 16 + l15;
                    const int slot = (kh * 4 + lh) ^ (rowb & 7);
                    bfr[fn] = *(const bf16x8v*)&sb[cur][kt][rowb * 64 + slot * 8];
                }
                #pragma unroll
                for (int fm = 0; fm < 2; ++fm)
                    #pragma unroll
                    for (int fn = 0; fn < 4; ++fn)
                        acc[fm][fn] = __builtin_amdgcn_mfma_f32_16x16x32_bf16(
                            af[fm], bfr[fn], acc[fm][fn], 0, 0, 0);
            }
        // store this bj's T tile (lane-contiguous 32B segments per (fm,r,fn))
        #pragma unroll
        for (int fm = 0; fm < 2; ++fm)
            #pragma unroll
            for (int r = 0; r < 4; ++r) {
                const int row = row0 + wrow * 32 + fm * 16 + lh * 4 + r;
                if (row < N_NODES) {
                    ushort* tp = T16 + ((size_t)bj * N_NODES + row) * 128 + wcol * 64 + l15;
                    #pragma unroll
                    for (int fn = 0; fn < 4; ++fn)
                        tp[fn * 16] = (ushort)f2bf(acc[fm][fn][r]);
                }
            }
        if (bj < 7)   // retire the 4 loads; 32 newest stores drain in shadow
            asm volatile("s_waitcnt vmcnt(32)\n\ts_barrier" ::: "memory");
    }
}

// ===== gather: out[n] = LNReLU( sum_e w*T[idx_e] + T[root][n] + bias ) ========
__global__ __launch_bounds__(256) void k_gather(const uint* __restrict__ T32,  // [8][N][64] dw
                                                const int* __restrict__ rp,
                                                const int* __restrict__ deg8,
                                                const uint* __restrict__ csr32,
                                                const float* __restrict__ bias,
                                                const float* __restrict__ g,
                                                const float* __restrict__ bb,
                                                uint* __restrict__ hout) {
    __shared__ float sinv[4][8];
    const int wave = (blockIdx.x * 256 + threadIdx.x) >> 6;
    const int lane = threadIdx.x & 63;
    const int wid = (threadIdx.x >> 6) & 3;
    const int nwaves = gridDim.x * 4;
    const float2 bias2 = *(const float2*)(bias + 2 * lane);
    const float2 g2 = *(const float2*)(g + 2 * lane);
    const float2 b2 = *(const float2*)(bb + 2 * lane);
    #pragma unroll 1
    for (int n0 = wave; n0 < N_NODES; n0 += nwaves) {
        const int n = __builtin_amdgcn_readfirstlane(n0);
        const int beg = __builtin_amdgcn_readfirstlane(rp[n]);
        const int end = __builtin_amdgcn_readfirstlane(rp[n + 1]);
        if (lane < 8) {
            const int c = deg8[(size_t)n * 8 + lane];
            sinv[wid][lane] = 1.0f / (float)max(c, 1);
        }
        float ax = 0.f, ay = 0.f;
        #pragma unroll 1
        for (int e = beg; e < end; e += 8) {            // masked 8-deep batch
            const int4 c0 = *(const int4*)(csr32 + e);
            const int4 c1 = *(const int4*)(csr32 + e + 4);
            int t[8] = {c0.x, c0.y, c0.z, c0.w, c1.x, c1.y, c1.z, c1.w};
            #pragma unroll
            for (int q = 0; q < 8; ++q) t[q] = __builtin_amdgcn_readfirstlane(t[q]);
            uint v[8];
            #pragma unroll
            for (int q = 0; q < 8; ++q)
                if (e + q < end) v[q] = T32[(size_t)(t[q] & 0xFFFFF) * 64 + lane];
            #pragma unroll
            for (int q = 0; q < 8; ++q)
                if (e + q < end) {
                    const float w = sinv[wid][(t[q] >> 20) & 7];
                    ax += w * __uint_as_float(v[q] << 16);
                    ay += w * __uint_as_float(v[q] & 0xFFFF0000u);
                }
        }
        const uint vr = T32[((size_t)7 * N_NODES + n) * 64 + lane];   // root term
        const float c0f = ax + bf2f(vr & 0xFFFFu) + bias2.x;
        const float c1f = ay + bf2f(vr >> 16) + bias2.y;
        float s = c0f + c1f, sq = c0f * c0f + c1f * c1f;
        #pragma unroll
        for (int o = 1; o < 64; o <<= 1) {
            s += __shfl_xor(s, o, 64);
            sq += __shfl_xor(sq, o, 64);
        }
        const float mean = s * (1.f / 128.f);
        const float var = sq * (1.f / 128.f) - mean * mean;
        const float rs = rsqrtf(var + LEPS);
        const float y0 = fmaxf((c0f - mean) * rs * g2.x + b2.x, 0.f);
        const float y1 = fmaxf((c1f - mean) * rs * g2.y + b2.y, 0.f);
        hout[(size_t)n * 64 + lane] = pack2(y0, y1);
    }
}

// ===== classifier: MFMA h@W1 + in-register LN/ReLU/W2-dot =====================
__global__ __launch_bounds__(256) void k_cls(const ushort* __restrict__ h16,
                                             const float* __restrict__ W1,
                                             const float* __restrict__ b1,
                                             const float* __restrict__ lg,
                                             const float* __restrict__ lb,
                                             const float* __restrict__ W2,
                                             const float* __restrict__ b2,
                                             float* __restrict__ outp, int nrows) {
    __shared__ ushort Bs[16 * 64 * 8];   // 16 KB
    const int tid = threadIdx.x;
    #pragma unroll
    for (int i = 0; i < 8; ++i) {
        const int q = i * 256 + tid;
        const int k = q >> 4;
        const int j0 = (q & 15) * 4;
        const float4 w = *(const float4*)(W1 + (size_t)k * 64 + j0);
        const int gg = k >> 3, kp = k & 7;
        const int jx = (gg & 3) << 4;
        Bs[(gg * 64 + ((j0 + 0) ^ jx)) * 8 + kp] = (ushort)f2bf(w.x);
        Bs[(gg * 64 + ((j0 + 1) ^ jx)) * 8 + kp] = (ushort)f2bf(w.y);
        Bs[(gg * 64 + ((j0 + 2) ^ jx)) * 8 + kp] = (ushort)f2bf(w.z);
        Bs[(gg * 64 + ((j0 + 3) ^ jx)) * 8 + kp] = (ushort)f2bf(w.w);
    }
    const int lane = tid & 63, wid = tid >> 6;
    const int l15 = lane & 15, lh = lane >> 4;
    float lgv[4], lbv[4], w2v[4], b1v[4];
    #pragma unroll
    for (int fn = 0; fn < 4; ++fn) {
        const int col = fn * 16 + l15;
        lgv[fn] = lg[col]; lbv[fn] = lb[col]; w2v[fn] = W2[col]; b1v[fn] = b1[col];
    }
    const float b2v = b2[0];
    __syncthreads();

    const int row0 = blockIdx.x * 128;
    f32x4v acc[2][4];
    #pragma unroll
    for (int fm = 0; fm < 2; ++fm)
        #pragma unroll
        for (int fn = 0; fn < 4; ++fn)
            acc[fm][fn] = (f32x4v){0.f, 0.f, 0.f, 0.f};

    #pragma unroll
    for (int kk = 0; kk < 4; ++kk) {
        bf16x8v af[2], bfr[4];
        #pragma unroll
        for (int fm = 0; fm < 2; ++fm) {
            const int row = min(row0 + wid * 32 + fm * 16 + l15, nrows - 1);
            af[fm] = *(const bf16x8v*)(h16 + (size_t)row * 128 + kk * 32 + lh * 8);
        }
        #pragma unroll
        for (int fn = 0; fn < 4; ++fn) {
            const int gg = kk * 4 + lh;
            const int jc = fn * 16 + l15;
            bfr[fn] = *(const bf16x8v*)&Bs[(gg * 64 + (jc ^ ((gg & 3) << 4))) * 8];
        }
        #pragma unroll
        for (int fm = 0; fm < 2; ++fm)
            #pragma unroll
            for (int fn = 0; fn < 4; ++fn)
                acc[fm][fn] = __builtin_amdgcn_mfma_f32_16x16x32_bf16(
                    af[fm], bfr[fn], acc[fm][fn], 0, 0, 0);
    }

    #pragma unroll
    for (int fm = 0; fm < 2; ++fm)
        #pragma unroll
        for (int r = 0; r < 4; ++r) {
            float cv[4];
            float s = 0.f, sq = 0.f;
            #pragma unroll
            for (int fn = 0; fn < 4; ++fn) {
                cv[fn] = acc[fm][fn][r] + b1v[fn];
                s += cv[fn]; sq += cv[fn] * cv[fn];
            }
            s += __shfl_xor(s, 1, 64); sq += __shfl_xor(sq, 1, 64);
            s += __shfl_xor(s, 2, 64); sq += __shfl_xor(sq, 2, 64);
            s += __shfl_xor(s, 4, 64); sq += __shfl_xor(sq, 4, 64);
            s += __shfl_xor(s, 8, 64); sq += __shfl_xor(sq, 8, 64);
            const float mean = s * (1.f / 64.f);
            const float var = sq * (1.f / 64.f) - mean * mean;
            const float rs = rsqrtf(var + LEPS);
            float dot = 0.f;
            #pragma unroll
            for (int fn = 0; fn < 4; ++fn)
                dot += fmaxf((cv[fn] - mean) * rs * lgv[fn] + lbv[fn], 0.f) * w2v[fn];
            dot += __shfl_xor(dot, 1, 64);
            dot += __shfl_xor(dot, 2, 64);
            dot += __shfl_xor(dot, 4, 64);
            dot += __shfl_xor(dot, 8, 64);
            const int row = row0 + wid * 32 + fm * 16 + lh * 4 + r;
            if (l15 == 0 && row < nrows) outp[row] = dot + b2v;
        }
}

extern "C" void kernel_launch(void* const* d_in, const int* in_sizes, int n_in,
                              void* d_out, int out_size, void* d_ws, size_t ws_size,
                              hipStream_t stream) {
    const float* x      = (const float*)d_in[0];
    const int*   eidx   = (const int*)d_in[1];
    const int*   etype  = (const int*)d_in[2];
    const float* emb_W  = (const float*)d_in[3];
    const float* emb_b  = (const float*)d_in[4];
    const float* rel_W  = (const float*)d_in[5];
    const float* root_W = (const float*)d_in[6];
    const float* conv_b = (const float*)d_in[7];
    const float* ln_g   = (const float*)d_in[8];
    const float* ln_b   = (const float*)d_in[9];
    const float* cls_W1 = (const float*)d_in[10];
    const float* cls_b1 = (const float*)d_in[11];
    const float* cls_lg = (const float*)d_in[12];
    const float* cls_lb = (const float*)d_in[13];
    const float* cls_W2 = (const float*)d_in[14];
    const float* cls_b2 = (const float*)d_in[15];

    const int* srcv = eidx;
    const int* dstv = eidx + N_EDGES;

    // workspace layout (~144 MB)
    char* ws = (char*)d_ws;
    size_t off = 0;
    auto alloc = [&](size_t bytes) { void* p = ws + off; off += (bytes + 255) & ~(size_t)255; return p; };
    ushort* h     = (ushort*)alloc((size_t)N_NODES * 128 * 2);          // bf16 h
    ushort* T     = (ushort*)alloc((size_t)8 * N_NODES * 128 * 2);      // bf16 T [8][N][128]
    int*    rp    = (int*)alloc((size_t)(N_NODES + 1) * 4);
    int*    cnts  = (int*)alloc((size_t)(N_NODES * 9) * 4);             // deg8 | fill
    uint*   csr32 = (uint*)alloc((size_t)(N_EDGES + 8) * 4);
    ushort* Btr   = (ushort*)alloc((size_t)2 * 8 * 128 * 128 * 2);      // bf16 W^T
    ushort* Bte   = (ushort*)alloc((size_t)128 * 64 * 2);               // bf16 emb_W^T
    int*    bs    = (int*)alloc(4096);
    int*    deg8  = cnts;
    int*    fill  = cnts + N_NODES * 8;
    (void)ws_size; (void)n_in; (void)in_sizes; (void)out_size;

    const int SB = (N_NODES + 255) / 256;         // 235

    hipMemsetAsync(deg8, 0, (size_t)(N_NODES * 8) * 4, stream);
    k_prep<<<66 + 1024, 256, 0, stream>>>(rel_W, root_W, emb_W, dstv, etype,
                                          Btr, Bte, deg8);
    k_scan1n<<<SB, 256, 0, stream>>>(deg8, rp, bs, N_NODES);
    k_scanmid<<<1, 256, 0, stream>>>(bs, SB);
    k_scanadd<<<SB, 256, 0, stream>>>(rp, bs, fill, N_NODES);
    k_emb<<<EMB_BLKS, 256, 0, stream>>>(x, Bte, emb_b, h);

    // layer 0: scatter co-scheduled with transform (independent work)
    k_trans8<<<SCAT_BLKS + ROW_BLKS, 512, 0, stream>>>(
        h, Btr, T, srcv, dstv, etype, fill, csr32, SCAT_BLKS);
    k_gather<<<2048, 256, 0, stream>>>(
        (const uint*)T, rp, deg8, csr32,
        conv_b, ln_g, ln_b, (uint*)h);

    // layer 1: transform only
    k_trans8<<<ROW_BLKS, 512, 0, stream>>>(
        h, Btr + (size_t)131072, T, srcv, dstv, etype, fill, csr32, 0);
    k_gather<<<2048, 256, 0, stream>>>(
        (const uint*)T, rp, deg8, csr32,
        conv_b + 128, ln_g + 128, ln_b + 128, (uint*)h);

    k_cls<<<469, 256, 0, stream>>>(h, cls_W1, cls_b1, cls_lg, cls_lb,
                                   cls_W2, cls_b2, (float*)d_out, N_NODES);
}

// Round 16
// 214.712 us; speedup vs baseline: 1.1223x; 1.0138x over previous
//
#include <hip/hip_runtime.h>
#include <hip/hip_bf16.h>

typedef unsigned int uint;
typedef unsigned short ushort;

#define N_NODES 60000
#define N_EDGES 600000
#define NREL 7
#define D_IN 64
#define DHID 128
#define LEPS 1e-5f
#define EMB_BLKS 938            // (N_NODES+63)/64
#define TR_BLKS 938             // (N_NODES+63)/64  (BM=64 transform tiles)
#define SCAT_BLKS 512           // scatter blocks inside k_trans8 (512 thr each)

typedef __attribute__((ext_vector_type(8))) short bf16x8v;   // 8 bf16 = 4 VGPRs
typedef __attribute__((ext_vector_type(4))) float f32x4v;    // MFMA accumulator

#define AS1C(p) ((const __attribute__((address_space(1))) void*)(p))
#define AS3(p)  ((__attribute__((address_space(3))) void*)(p))

__device__ __forceinline__ float bf2f(uint u16) {
    return __uint_as_float(u16 << 16);
}
__device__ __forceinline__ uint f2bf(float f) {
    uint u = __float_as_uint(f);
    uint lsb = (u >> 16) & 1u;
    u += 0x7fffu + lsb;
    return u >> 16;
}
__device__ __forceinline__ uint pack2(float a, float b) {
    return f2bf(a) | (f2bf(b) << 16);
}

// ===== prep: blocks 0..63 W transposes, 64..65 emb_W transpose, 66+ deg8 ======
__global__ __launch_bounds__(256) void k_prep(const float* __restrict__ relW,
                                              const float* __restrict__ rootW,
                                              const float* __restrict__ embW,
                                              const int* __restrict__ dst,
                                              const int* __restrict__ et,
                                              ushort* __restrict__ Btr,   // [2][8][128j][128k]
                                              ushort* __restrict__ Bte,   // [128][64]
                                              int* __restrict__ deg8) {
    __shared__ float t[64][65];
    const int tid = threadIdx.x;
    if (blockIdx.x < 64) {
        const int l  = blockIdx.x >> 5;
        const int b5 = blockIdx.x & 31;
        const int r  = b5 >> 2;              // 0..7 (7 = root)
        const int kt = (b5 >> 1) & 1;
        const int jt = b5 & 1;
        #pragma unroll
        for (int i = 0; i < 4; ++i) {
            const int idx = i * 256 + tid;   // 0..1023
            const int kr = idx >> 4;         // 0..63
            const int j4 = idx & 15;
            const int kg = kt * 64 + kr;
            const float* src = (r < 7)
                ? (relW + (((size_t)l * 7 + r) * 128 + kg) * 128 + jt * 64 + j4 * 4)
                : (rootW + ((size_t)l * 128 + kg) * 128 + jt * 64 + j4 * 4);
            const float4 v = *(const float4*)src;
            t[kr][j4 * 4 + 0] = v.x; t[kr][j4 * 4 + 1] = v.y;
            t[kr][j4 * 4 + 2] = v.z; t[kr][j4 * 4 + 3] = v.w;
        }
        __syncthreads();
        uint* btd = (uint*)Btr;
        #pragma unroll
        for (int i = 0; i < 8; ++i) {
            const int idx = i * 256 + tid;   // 0..2047
            const int jr = idx >> 5;         // 0..63
            const int kd = idx & 31;         // k-dword within 64-k tile
            const uint w = pack2(t[kd * 2][jr], t[kd * 2 + 1][jr]);
            btd[((size_t)(l * 8 + r) * 128 + jt * 64 + jr) * 64 + kt * 32 + kd] = w;
        }
    } else if (blockIdx.x < 66) {
        const int jt = blockIdx.x - 64;      // 0..1
        #pragma unroll
        for (int i = 0; i < 4; ++i) {
            const int idx = i * 256 + tid;
            const int kr = idx >> 4;
            const int j4 = idx & 15;
            const float4 v = *(const float4*)(embW + (size_t)kr * 128 + jt * 64 + j4 * 4);
            t[kr][j4 * 4 + 0] = v.x; t[kr][j4 * 4 + 1] = v.y;
            t[kr][j4 * 4 + 2] = v.z; t[kr][j4 * 4 + 3] = v.w;
        }
        __syncthreads();
        uint* btd = (uint*)Bte;
        #pragma unroll
        for (int i = 0; i < 8; ++i) {
            const int idx = i * 256 + tid;
            const int jr = idx >> 5;
            const int kd = idx & 31;
            const uint w = pack2(t[kd * 2][jr], t[kd * 2 + 1][jr]);
            btd[(size_t)(jt * 64 + jr) * 32 + kd] = w;
        }
    } else {
        for (int e = (blockIdx.x - 66) * 256 + tid; e < N_EDGES; e += 1024 * 256)
            atomicAdd(&deg8[dst[e] * 8 + et[e]], 1);
    }
}

// ===== scan: node degree derived from deg8 row sums, exclusive scan ==========
__global__ void k_scan1n(const int* __restrict__ deg8, int* __restrict__ rp,
                         int* __restrict__ bsum, int n) {
    __shared__ int s[256];
    const int t = threadIdx.x;
    const int i = blockIdx.x * 256 + t;
    int v = 0;
    if (i < n) {
        const int4 x = *(const int4*)(deg8 + (size_t)i * 8);
        const int4 y = *(const int4*)(deg8 + (size_t)i * 8 + 4);
        v = x.x + x.y + x.z + x.w + y.x + y.y + y.z + y.w;
    }
    s[t] = v;
    __syncthreads();
    for (int o = 1; o < 256; o <<= 1) {
        int uu = (t >= o) ? s[t - o] : 0;
        __syncthreads();
        s[t] += uu;
        __syncthreads();
    }
    if (i < n) rp[i] = s[t] - v;
    if (t == 255) bsum[blockIdx.x] = s[255];
}
__global__ void k_scanmid(int* __restrict__ bs, int nb) {
    __shared__ int s[256];
    __shared__ int carrys;
    const int t = threadIdx.x;
    if (t == 0) carrys = 0;
    __syncthreads();
    const int nch = (nb + 255) / 256;
    for (int ch = 0; ch < nch; ++ch) {
        const int i = ch * 256 + t;
        const int v = (i < nb) ? bs[i] : 0;
        s[t] = v;
        __syncthreads();
        for (int o = 1; o < 256; o <<= 1) {
            int uu = (t >= o) ? s[t - o] : 0;
            __syncthreads();
            s[t] += uu;
            __syncthreads();
        }
        const int carry = carrys;
        if (i < nb) bs[i] = s[t] - v + carry;
        __syncthreads();
        if (t == 255) carrys = carry + s[255];
        __syncthreads();
    }
}
// final scan add; also pre-initializes fill = rp (scatter atomic returns position)
__global__ void k_scanadd(int* __restrict__ a, const int* __restrict__ bsums,
                          int* __restrict__ fill, int n) {
    const int i = blockIdx.x * 256 + threadIdx.x;
    if (i < n) {
        const int v = a[i] + bsums[blockIdx.x];
        a[i] = v;
        fill[i] = v;
    }
    if (blockIdx.x == 0 && threadIdx.x == 0) a[n] = N_EDGES;
}

// ===== emb: h0 = clip(x,-10,10)@emb_W + emb_b (bf16), MFMA =====================
__global__ __launch_bounds__(256) void k_emb(const float* __restrict__ x,
                                             const ushort* __restrict__ Bte,
                                             const float* __restrict__ ebias,
                                             ushort* __restrict__ h) {
    __shared__ alignas(16) ushort sa[64 * 64];    // 8 KB
    __shared__ alignas(16) ushort sb[128 * 64];   // 16 KB
    const int tid = threadIdx.x;
    const int lane = tid & 63;
    const int wid = tid >> 6;
    const int wrow = wid >> 1, wcol = wid & 1;
    const int l15 = lane & 15, lh = lane >> 4;
    const int row0 = blockIdx.x * 64;

    #pragma unroll
    for (int i = 0; i < 2; ++i) {
        const int p = i * 256 + tid;
        const int row = p >> 3, gq = p & 7;
        const int n = min(row0 + row, N_NODES - 1);
        const float4 xa = *(const float4*)(x + (size_t)n * 64 + gq * 8);
        const float4 xb = *(const float4*)(x + (size_t)n * 64 + gq * 8 + 4);
        uint w[4];
        w[0] = pack2(fminf(fmaxf(xa.x, -10.f), 10.f), fminf(fmaxf(xa.y, -10.f), 10.f));
        w[1] = pack2(fminf(fmaxf(xa.z, -10.f), 10.f), fminf(fmaxf(xa.w, -10.f), 10.f));
        w[2] = pack2(fminf(fmaxf(xb.x, -10.f), 10.f), fminf(fmaxf(xb.y, -10.f), 10.f));
        w[3] = pack2(fminf(fmaxf(xb.z, -10.f), 10.f), fminf(fmaxf(xb.w, -10.f), 10.f));
        *(uint4*)&sa[(row * 8 + (gq ^ (row & 7))) * 8] = make_uint4(w[0], w[1], w[2], w[3]);
    }
    #pragma unroll
    for (int i = 0; i < 4; ++i) {
        const int p = i * 256 + tid;
        const int row = p >> 3, gq = p & 7;
        const uint4 v = *(const uint4*)((const uint*)Bte + (size_t)row * 32 + gq * 4);
        *(uint4*)&sb[(row * 8 + (gq ^ (row & 7))) * 8] = v;
    }
    float bv[4];
    #pragma unroll
    for (int fn = 0; fn < 4; ++fn) bv[fn] = ebias[wcol * 64 + fn * 16 + l15];
    __syncthreads();

    f32x4v acc[2][4];
    #pragma unroll
    for (int fm = 0; fm < 2; ++fm)
        #pragma unroll
        for (int fn = 0; fn < 4; ++fn)
            acc[fm][fn] = (f32x4v){0.f, 0.f, 0.f, 0.f};
    #pragma unroll
    for (int kh = 0; kh < 2; ++kh) {
        bf16x8v af[2], bfr[4];
        #pragma unroll
        for (int fm = 0; fm < 2; ++fm) {
            const int rowa = wrow * 32 + fm * 16 + l15;
            const int slot = (kh * 4 + lh) ^ (rowa & 7);
            af[fm] = *(const bf16x8v*)&sa[rowa * 64 + slot * 8];
        }
        #pragma unroll
        for (int fn = 0; fn < 4; ++fn) {
            const int rowb = wcol * 64 + fn * 16 + l15;
            const int slot = (kh * 4 + lh) ^ (rowb & 7);
            bfr[fn] = *(const bf16x8v*)&sb[rowb * 64 + slot * 8];
        }
        #pragma unroll
        for (int fm = 0; fm < 2; ++fm)
            #pragma unroll
            for (int fn = 0; fn < 4; ++fn)
                acc[fm][fn] = __builtin_amdgcn_mfma_f32_16x16x32_bf16(
                    af[fm], bfr[fn], acc[fm][fn], 0, 0, 0);
    }
    #pragma unroll
    for (int fm = 0; fm < 2; ++fm)
        #pragma unroll
        for (int r = 0; r < 4; ++r) {
            const int row = row0 + wrow * 32 + fm * 16 + lh * 4 + r;
            if (row < N_NODES) {
                #pragma unroll
                for (int fn = 0; fn < 4; ++fn) {
                    const int col = wcol * 64 + fn * 16 + l15;
                    h[(size_t)row * 128 + col] = (ushort)f2bf(acc[fm][fn][r] + bv[fn]);
                }
            }
        }
}

// ===== trans8 v3: blocks < nscat do CSR scatter; rest: ONE block = 64 h-rows,
// loops ALL 8 bj from one LDS A-tile. 80 KB LDS -> 2 blocks/CU (16 waves) for
// store-throughput. 8 waves = 2 node-bands(32) x 4 j-bands(32), acc[2][2].
// Pipeline: stageB(next) -> MFMA -> stores -> vmcnt(16)+barrier. =============
// entry = (rel<<20) | (rel*N_NODES + src)
__global__ __launch_bounds__(512) void k_trans8(const ushort* __restrict__ h16,
                                                const ushort* __restrict__ Btr,  // [8][128j][128k]
                                                ushort* __restrict__ T16,        // [8][N][128]
                                                const int* __restrict__ src,
                                                const int* __restrict__ dst,
                                                const int* __restrict__ et,
                                                int* __restrict__ fill,
                                                uint* __restrict__ csr32,
                                                int nscat) {
    __shared__ alignas(16) ushort sa[2][4096];      // 16 KB: h-tile [kt][64r*64]
    __shared__ alignas(16) ushort sb[2][2][8192];   // 64 KB: W [buf][kt][128j*64]
    const int tid = threadIdx.x;
    if (blockIdx.x < nscat) {
        for (int e = blockIdx.x * 512 + tid; e < N_EDGES; e += SCAT_BLKS * 512) {
            const int d = dst[e];
            const int r = et[e];
            const int p = atomicAdd(&fill[d], 1);
            csr32[p] = ((uint)r << 20) | (uint)(r * N_NODES + src[e]);
        }
        return;
    }
    const int row0 = (blockIdx.x - nscat) * 64;
    const int lane = tid & 63;
    const int wid = tid >> 6;
    const int wrow = wid >> 2;        // 0..1: 32-node band
    const int wcol = wid & 3;         // 0..3: 32-j band
    const int l15 = lane & 15, lh = lane >> 4;

    // A staging: 512 granules/kt; thread covers granule pA = wid*64+lane
    const int pA = wid * 64 + lane;
    const int rA = pA >> 3;
    const int gA = (pA & 7) ^ (rA & 7);
    const int awA = min(row0 + rA, N_NODES - 1);
    // B staging: 1024 granules/kt; thread covers {hf*512 + wid*64 + lane}
    int rB[2], gB[2];
    #pragma unroll
    for (int hf = 0; hf < 2; ++hf) {
        const int p = hf * 512 + wid * 64 + lane;
        const int r = p >> 3;
        rB[hf] = r;
        gB[hf] = (p & 7) ^ (r & 7);
    }
    auto stageA = [&]() {
        #pragma unroll
        for (int kt = 0; kt < 2; ++kt) {
            const ushort* ga = h16 + (size_t)awA * 128 + kt * 64 + gA * 8;
            __builtin_amdgcn_global_load_lds(AS1C(ga),
                AS3(&sa[kt][(wid * 64) * 8]), 16, 0, 0);
        }
    };
    auto stageB = [&](int buf, int bj) {
        #pragma unroll
        for (int kt = 0; kt < 2; ++kt)
            #pragma unroll
            for (int hf = 0; hf < 2; ++hf) {
                const ushort* gb = Btr + ((size_t)bj * 128 + rB[hf]) * 128 + kt * 64 + gB[hf] * 8;
                __builtin_amdgcn_global_load_lds(AS1C(gb),
                    AS3(&sb[buf][kt][(hf * 512 + wid * 64) * 8]), 16, 0, 0);
            }
    };

    stageA();          // 2 outstanding
    stageB(0, 0);      // 6 outstanding
    asm volatile("s_waitcnt vmcnt(0)\n\ts_barrier" ::: "memory");

    #pragma unroll 1
    for (int bj = 0; bj < 8; ++bj) {
        const int cur = bj & 1;
        if (bj < 7) stageB(cur ^ 1, bj + 1);   // 4 loads into sb[cur^1]
        f32x4v acc[2][2];
        #pragma unroll
        for (int fm = 0; fm < 2; ++fm)
            #pragma unroll
            for (int fn = 0; fn < 2; ++fn)
                acc[fm][fn] = (f32x4v){0.f, 0.f, 0.f, 0.f};
        #pragma unroll
        for (int kt = 0; kt < 2; ++kt)
            #pragma unroll
            for (int kh = 0; kh < 2; ++kh) {
                bf16x8v af[2], bfr[2];
                #pragma unroll
                for (int fm = 0; fm < 2; ++fm) {        // A = h rows (n)
                    const int rowa = wrow * 32 + fm * 16 + l15;
                    const int slot = (kh * 4 + lh) ^ (rowa & 7);
                    af[fm] = *(const bf16x8v*)&sa[kt][rowa * 64 + slot * 8];
                }
                #pragma unroll
                for (int fn = 0; fn < 2; ++fn) {        // B = W rows (j)
                    const int rowb = wcol * 32 + fn * 16 + l15;
                    const int slot = (kh * 4 + lh) ^ (rowb & 7);
                    bfr[fn] = *(const bf16x8v*)&sb[cur][kt][rowb * 64 + slot * 8];
                }
                #pragma unroll
                for (int fm = 0; fm < 2; ++fm)
                    #pragma unroll
                    for (int fn = 0; fn < 2; ++fn)
                        acc[fm][fn] = __builtin_amdgcn_mfma_f32_16x16x32_bf16(
                            af[fm], bfr[fn], acc[fm][fn], 0, 0, 0);
            }
        // store this bj's T tile (lane-contiguous 32B segments per (fm,r,fn))
        #pragma unroll
        for (int fm = 0; fm < 2; ++fm)
            #pragma unroll
            for (int r = 0; r < 4; ++r) {
                const int row = row0 + wrow * 32 + fm * 16 + lh * 4 + r;
                if (row < N_NODES) {
                    ushort* tp = T16 + ((size_t)bj * N_NODES + row) * 128 + wcol * 32 + l15;
                    #pragma unroll
                    for (int fn = 0; fn < 2; ++fn)
                        tp[fn * 16] = (ushort)f2bf(acc[fm][fn][r]);
                }
            }
        if (bj < 7)   // retire the 4 loads; 16 newest stores drain in shadow
            asm volatile("s_waitcnt vmcnt(16)\n\ts_barrier" ::: "memory");
    }
}

// ===== gather: out[n] = LNReLU( sum_e w*T[idx_e] + T[root][n] + bias ) ========
__global__ __launch_bounds__(256) void k_gather(const uint* __restrict__ T32,  // [8][N][64] dw
                                                const int* __restrict__ rp,
                                                const int* __restrict__ deg8,
                                                const uint* __restrict__ csr32,
                                                const float* __restrict__ bias,
                                                const float* __restrict__ g,
                                                const float* __restrict__ bb,
                                                uint* __restrict__ hout) {
    __shared__ float sinv[4][8];
    const int wave = (blockIdx.x * 256 + threadIdx.x) >> 6;
    const int lane = threadIdx.x & 63;
    const int wid = (threadIdx.x >> 6) & 3;
    const int nwaves = gridDim.x * 4;
    const float2 bias2 = *(const float2*)(bias + 2 * lane);
    const float2 g2 = *(const float2*)(g + 2 * lane);
    const float2 b2 = *(const float2*)(bb + 2 * lane);
    #pragma unroll 1
    for (int n0 = wave; n0 < N_NODES; n0 += nwaves) {
        const int n = __builtin_amdgcn_readfirstlane(n0);
        const int beg = __builtin_amdgcn_readfirstlane(rp[n]);
        const int end = __builtin_amdgcn_readfirstlane(rp[n + 1]);
        if (lane < 8) {
            const int c = deg8[(size_t)n * 8 + lane];
            sinv[wid][lane] = 1.0f / (float)max(c, 1);
        }
        float ax = 0.f, ay = 0.f;
        #pragma unroll 1
        for (int e = beg; e < end; e += 8) {            // masked 8-deep batch
            const int4 c0 = *(const int4*)(csr32 + e);
            const int4 c1 = *(const int4*)(csr32 + e + 4);
            int t[8] = {c0.x, c0.y, c0.z, c0.w, c1.x, c1.y, c1.z, c1.w};
            #pragma unroll
            for (int q = 0; q < 8; ++q) t[q] = __builtin_amdgcn_readfirstlane(t[q]);
            uint v[8];
            #pragma unroll
            for (int q = 0; q < 8; ++q)
                if (e + q < end) v[q] = T32[(size_t)(t[q] & 0xFFFFF) * 64 + lane];
            #pragma unroll
            for (int q = 0; q < 8; ++q)
                if (e + q < end) {
                    const float w = sinv[wid][(t[q] >> 20) & 7];
                    ax += w * __uint_as_float(v[q] << 16);
                    ay += w * __uint_as_float(v[q] & 0xFFFF0000u);
                }
        }
        const uint vr = T32[((size_t)7 * N_NODES + n) * 64 + lane];   // root term
        const float c0f = ax + bf2f(vr & 0xFFFFu) + bias2.x;
        const float c1f = ay + bf2f(vr >> 16) + bias2.y;
        float s = c0f + c1f, sq = c0f * c0f + c1f * c1f;
        #pragma unroll
        for (int o = 1; o < 64; o <<= 1) {
            s += __shfl_xor(s, o, 64);
            sq += __shfl_xor(sq, o, 64);
        }
        const float mean = s * (1.f / 128.f);
        const float var = sq * (1.f / 128.f) - mean * mean;
        const float rs = rsqrtf(var + LEPS);
        const float y0 = fmaxf((c0f - mean) * rs * g2.x + b2.x, 0.f);
        const float y1 = fmaxf((c1f - mean) * rs * g2.y + b2.y, 0.f);
        hout[(size_t)n * 64 + lane] = pack2(y0, y1);
    }
}

// ===== classifier: MFMA h@W1 + in-register LN/ReLU/W2-dot =====================
__global__ __launch_bounds__(256) void k_cls(const ushort* __restrict__ h16,
                                             const float* __restrict__ W1,
                                             const float* __restrict__ b1,
                                             const float* __restrict__ lg,
                                             const float* __restrict__ lb,
                                             const float* __restrict__ W2,
                                             const float* __restrict__ b2,
                                             float* __restrict__ outp, int nrows) {
    __shared__ ushort Bs[16 * 64 * 8];   // 16 KB
    const int tid = threadIdx.x;
    #pragma unroll
    for (int i = 0; i < 8; ++i) {
        const int q = i * 256 + tid;
        const int k = q >> 4;
        const int j0 = (q & 15) * 4;
        const float4 w = *(const float4*)(W1 + (size_t)k * 64 + j0);
        const int gg = k >> 3, kp = k & 7;
        const int jx = (gg & 3) << 4;
        Bs[(gg * 64 + ((j0 + 0) ^ jx)) * 8 + kp] = (ushort)f2bf(w.x);
        Bs[(gg * 64 + ((j0 + 1) ^ jx)) * 8 + kp] = (ushort)f2bf(w.y);
        Bs[(gg * 64 + ((j0 + 2) ^ jx)) * 8 + kp] = (ushort)f2bf(w.z);
        Bs[(gg * 64 + ((j0 + 3) ^ jx)) * 8 + kp] = (ushort)f2bf(w.w);
    }
    const int lane = tid & 63, wid = tid >> 6;
    const int l15 = lane & 15, lh = lane >> 4;
    float lgv[4], lbv[4], w2v[4], b1v[4];
    #pragma unroll
    for (int fn = 0; fn < 4; ++fn) {
        const int col = fn * 16 + l15;
        lgv[fn] = lg[col]; lbv[fn] = lb[col]; w2v[fn] = W2[col]; b1v[fn] = b1[col];
    }
    const float b2v = b2[0];
    __syncthreads();

    const int row0 = blockIdx.x * 128;
    f32x4v acc[2][4];
    #pragma unroll
    for (int fm = 0; fm < 2; ++fm)
        #pragma unroll
        for (int fn = 0; fn < 4; ++fn)
            acc[fm][fn] = (f32x4v){0.f, 0.f, 0.f, 0.f};

    #pragma unroll
    for (int kk = 0; kk < 4; ++kk) {
        bf16x8v af[2], bfr[4];
        #pragma unroll
        for (int fm = 0; fm < 2; ++fm) {
            const int row = min(row0 + wid * 32 + fm * 16 + l15, nrows - 1);
            af[fm] = *(const bf16x8v*)(h16 + (size_t)row * 128 + kk * 32 + lh * 8);
        }
        #pragma unroll
        for (int fn = 0; fn < 4; ++fn) {
            const int gg = kk * 4 + lh;
            const int jc = fn * 16 + l15;
            bfr[fn] = *(const bf16x8v*)&Bs[(gg * 64 + (jc ^ ((gg & 3) << 4))) * 8];
        }
        #pragma unroll
        for (int fm = 0; fm < 2; ++fm)
            #pragma unroll
            for (int fn = 0; fn < 4; ++fn)
                acc[fm][fn] = __builtin_amdgcn_mfma_f32_16x16x32_bf16(
                    af[fm], bfr[fn], acc[fm][fn], 0, 0, 0);
    }

    #pragma unroll
    for (int fm = 0; fm < 2; ++fm)
        #pragma unroll
        for (int r = 0; r < 4; ++r) {
            float cv[4];
            float s = 0.f, sq = 0.f;
            #pragma unroll
            for (int fn = 0; fn < 4; ++fn) {
                cv[fn] = acc[fm][fn][r] + b1v[fn];
                s += cv[fn]; sq += cv[fn] * cv[fn];
            }
            s += __shfl_xor(s, 1, 64); sq += __shfl_xor(sq, 1, 64);
            s += __shfl_xor(s, 2, 64); sq += __shfl_xor(sq, 2, 64);
            s += __shfl_xor(s, 4, 64); sq += __shfl_xor(sq, 4, 64);
            s += __shfl_xor(s, 8, 64); sq += __shfl_xor(sq, 8, 64);
            const float mean = s * (1.f / 64.f);
            const float var = sq * (1.f / 64.f) - mean * mean;
            const float rs = rsqrtf(var + LEPS);
            float dot = 0.f;
            #pragma unroll
            for (int fn = 0; fn < 4; ++fn)
                dot += fmaxf((cv[fn] - mean) * rs * lgv[fn] + lbv[fn], 0.f) * w2v[fn];
            dot += __shfl_xor(dot, 1, 64);
            dot += __shfl_xor(dot, 2, 64);
            dot += __shfl_xor(dot, 4, 64);
            dot += __shfl_xor(dot, 8, 64);
            const int row = row0 + wid * 32 + fm * 16 + lh * 4 + r;
            if (l15 == 0 && row < nrows) outp[row] = dot + b2v;
        }
}

extern "C" void kernel_launch(void* const* d_in, const int* in_sizes, int n_in,
                              void* d_out, int out_size, void* d_ws, size_t ws_size,
                              hipStream_t stream) {
    const float* x      = (const float*)d_in[0];
    const int*   eidx   = (const int*)d_in[1];
    const int*   etype  = (const int*)d_in[2];
    const float* emb_W  = (const float*)d_in[3];
    const float* emb_b  = (const float*)d_in[4];
    const float* rel_W  = (const float*)d_in[5];
    const float* root_W = (const float*)d_in[6];
    const float* conv_b = (const float*)d_in[7];
    const float* ln_g   = (const float*)d_in[8];
    const float* ln_b   = (const float*)d_in[9];
    const float* cls_W1 = (const float*)d_in[10];
    const float* cls_b1 = (const float*)d_in[11];
    const float* cls_lg = (const float*)d_in[12];
    const float* cls_lb = (const float*)d_in[13];
    const float* cls_W2 = (const float*)d_in[14];
    const float* cls_b2 = (const float*)d_in[15];

    const int* srcv = eidx;
    const int* dstv = eidx + N_EDGES;

    // workspace layout (~144 MB)
    char* ws = (char*)d_ws;
    size_t off = 0;
    auto alloc = [&](size_t bytes) { void* p = ws + off; off += (bytes + 255) & ~(size_t)255; return p; };
    ushort* h     = (ushort*)alloc((size_t)N_NODES * 128 * 2);          // bf16 h
    ushort* T     = (ushort*)alloc((size_t)8 * N_NODES * 128 * 2);      // bf16 T [8][N][128]
    int*    rp    = (int*)alloc((size_t)(N_NODES + 1) * 4);
    int*    cnts  = (int*)alloc((size_t)(N_NODES * 9) * 4);             // deg8 | fill
    uint*   csr32 = (uint*)alloc((size_t)(N_EDGES + 8) * 4);
    ushort* Btr   = (ushort*)alloc((size_t)2 * 8 * 128 * 128 * 2);      // bf16 W^T
    ushort* Bte   = (ushort*)alloc((size_t)128 * 64 * 2);               // bf16 emb_W^T
    int*    bs    = (int*)alloc(4096);
    int*    deg8  = cnts;
    int*    fill  = cnts + N_NODES * 8;
    (void)ws_size; (void)n_in; (void)in_sizes; (void)out_size;

    const int SB = (N_NODES + 255) / 256;         // 235

    hipMemsetAsync(deg8, 0, (size_t)(N_NODES * 8) * 4, stream);
    k_prep<<<66 + 1024, 256, 0, stream>>>(rel_W, root_W, emb_W, dstv, etype,
                                          Btr, Bte, deg8);
    k_scan1n<<<SB, 256, 0, stream>>>(deg8, rp, bs, N_NODES);
    k_scanmid<<<1, 256, 0, stream>>>(bs, SB);
    k_scanadd<<<SB, 256, 0, stream>>>(rp, bs, fill, N_NODES);
    k_emb<<<EMB_BLKS, 256, 0, stream>>>(x, Bte, emb_b, h);

    // layer 0: scatter co-scheduled with transform (independent work)
    k_trans8<<<SCAT_BLKS + TR_BLKS, 512, 0, stream>>>(
        h, Btr, T, srcv, dstv, etype, fill, csr32, SCAT_BLKS);
    k_gather<<<2048, 256, 0, stream>>>(
        (const uint*)T, rp, deg8, csr32,
        conv_b, ln_g, ln_b, (uint*)h);

    // layer 1: transform only
    k_trans8<<<TR_BLKS, 512, 0, stream>>>(
        h, Btr + (size_t)131072, T, srcv, dstv, etype, fill, csr32, 0);
    k_gather<<<2048, 256, 0, stream>>>(
        (const uint*)T, rp, deg8, csr32,
        conv_b + 128, ln_g + 128, ln_b + 128, (uint*)h);

    k_cls<<<469, 256, 0, stream>>>(h, cls_W1, cls_b1, cls_lg, cls_lb,
                                   cls_W2, cls_b2, (float*)d_out, N_NODES);
}